// Round 7
// baseline (132.157 us; speedup 1.0000x reference)
//
#include <hip/hip_runtime.h>

// WaveletLayer on [4096,4096] fp32:
//   out = diag_s * DWT3( diag_g * (DWT3(diag_b * x))[perm] )
// Haar DWT3 packet layout: [cA3(512) | cD3(512) | cD2(1024) | cD1(2048)].
//
// R7 structure: 256 threads, R=2 rows/block (thread owns 16 contiguous
// columns of both rows). DWTs fully in registers. Permutation LDS
// round-trip vectorized across rows: one ds_write_b64 / random ds_read_b64
// per coefficient serves both rows; 1 barrier/block. 32 KB LDS + VGPR<=128
// (__launch_bounds__(256,4)) => 4 blocks/CU resident, 2048 blocks = 8
// slots/CU — double the concurrent latency chains of R6 (which was
// latency-bound with every pipe <36% busy).

#define D   4096
#define NT  256            // 16 columns / thread
#define R   2              // rows per block

#define C_INV_SQRT2 0.70710678118654752440f

typedef float vf2 __attribute__((ext_vector_type(2)));
typedef float vf4 __attribute__((ext_vector_type(4)));

// vf2-block-index swizzle: spreads positions across the 16 bank-pairs
static __device__ __forceinline__ int swzB(int p) {
    return p ^ ((p >> 4) & 15);
}

// 3 in-register Haar levels on 16 contiguous elements.
// Output packed: c[0..1]=cA3(@2t), c[2..3]=cD3(@512+2t),
// c[4..7]=cD2(@1024+4t), c[8..15]=cD1(@2048+8t).
static __device__ __forceinline__ void dwt3_reg(const float v[16], float c[16]) {
    float a1[8];
    #pragma unroll
    for (int j = 0; j < 8; ++j) {
        a1[j]    = (v[2 * j] + v[2 * j + 1]) * C_INV_SQRT2;
        c[8 + j] = (v[2 * j] - v[2 * j + 1]) * C_INV_SQRT2;   // d1
    }
    float a2[4];
    #pragma unroll
    for (int j = 0; j < 4; ++j) {
        a2[j]    = (a1[2 * j] + a1[2 * j + 1]) * C_INV_SQRT2;
        c[4 + j] = (a1[2 * j] - a1[2 * j + 1]) * C_INV_SQRT2; // d2
    }
    #pragma unroll
    for (int j = 0; j < 2; ++j) {
        c[j]     = (a2[2 * j] + a2[2 * j + 1]) * C_INV_SQRT2; // a3
        c[2 + j] = (a2[2 * j] - a2[2 * j + 1]) * C_INV_SQRT2; // d3
    }
}

__global__ __launch_bounds__(NT, 4) void wavelet_rows_kernel(
    const float* __restrict__ x,
    const float* __restrict__ diag_s,
    const float* __restrict__ diag_g,
    const float* __restrict__ diag_b,
    const int*   __restrict__ perm,
    float*       __restrict__ out)
{
    __shared__ vf2 lds2[D];    // 32 KB: [coef position][row 0..1]

    const int t = threadIdx.x;
    const size_t row0 = (size_t)blockIdx.x * R;

    // ---- register-cache row-invariant tables ----
    float db[16], dg[16];
    int   pidx[16];
    {
        const vf4* b4 = (const vf4*)diag_b;
        const vf4* g4 = (const vf4*)diag_g;
        const int4* p4 = (const int4*)perm;
        #pragma unroll
        for (int k = 0; k < 4; ++k) {
            vf4 bv = b4[4 * t + k];
            db[4 * k + 0] = bv.x; db[4 * k + 1] = bv.y;
            db[4 * k + 2] = bv.z; db[4 * k + 3] = bv.w;
            vf4 gv = g4[4 * t + k];
            dg[4 * k + 0] = gv.x; dg[4 * k + 1] = gv.y;
            dg[4 * k + 2] = gv.z; dg[4 * k + 3] = gv.w;
            int4 pv = p4[4 * t + k];
            pidx[4 * k + 0] = pv.x; pidx[4 * k + 1] = pv.y;
            pidx[4 * k + 2] = pv.z; pidx[4 * k + 3] = pv.w;
        }
    }

    // ---- per-row: load x, DWT #1 in registers (x regs are transient) ----
    float cf[R][16];
    #pragma unroll
    for (int r = 0; r < R; ++r) {
        const vf4* x4 = (const vf4*)(x + (row0 + r) * (size_t)D);
        vf4 xv[4];
        #pragma unroll
        for (int k = 0; k < 4; ++k) xv[k] = x4[4 * t + k];
        float v[16];
        #pragma unroll
        for (int k = 0; k < 4; ++k) {
            v[4 * k + 0] = xv[k].x * db[4 * k + 0];
            v[4 * k + 1] = xv[k].y * db[4 * k + 1];
            v[4 * k + 2] = xv[k].z * db[4 * k + 2];
            v[4 * k + 3] = xv[k].w * db[4 * k + 3];
        }
        dwt3_reg(v, cf[r]);
    }

    // ---- scatter: one b64 per coefficient position (both rows) ----
    {
        int pos[16];
        #pragma unroll
        for (int j = 0; j < 2; ++j) pos[j]     = 2 * t + j;
        #pragma unroll
        for (int j = 0; j < 2; ++j) pos[2 + j] = 512 + 2 * t + j;
        #pragma unroll
        for (int j = 0; j < 4; ++j) pos[4 + j] = 1024 + 4 * t + j;
        #pragma unroll
        for (int j = 0; j < 8; ++j) pos[8 + j] = 2048 + 8 * t + j;
        #pragma unroll
        for (int k = 0; k < 16; ++k) {
            vf2 c2;
            c2.x = cf[0][k]; c2.y = cf[1][k];
            lds2[swzB(pos[k])] = c2;
        }
    }

    __syncthreads();   // the only barrier

    // ---- gather: one random b64 per perm index serves both rows ----
    float w[R][16];
    #pragma unroll
    for (int k = 0; k < 16; ++k) {
        vf2 f = lds2[swzB(pidx[k])];
        w[0][k] = f.x * dg[k];
        w[1][k] = f.y * dg[k];
    }

    // ---- DWT #2 per row + diag_s + store ----
    const vf2* s2 = (const vf2*)diag_s;
    const vf4* s4 = (const vf4*)diag_s;

    #pragma unroll
    for (int r = 0; r < R; ++r) {
        float e[16];
        dwt3_reg(w[r], e);

        float* orow = out + (row0 + r) * (size_t)D;
        vf2* o2 = (vf2*)orow;
        vf4* o4 = (vf4*)orow;
        vf2 sv, ov;
        sv = s2[t];                       // cA3
        ov.x = e[0] * sv.x; ov.y = e[1] * sv.y;
        o2[t] = ov;
        sv = s2[256 + t];                 // cD3
        ov.x = e[2] * sv.x; ov.y = e[3] * sv.y;
        o2[256 + t] = ov;
        vf4 sw, o;
        sw = s4[256 + t];                 // cD2
        o.x = e[4] * sw.x; o.y = e[5] * sw.y;
        o.z = e[6] * sw.z; o.w = e[7] * sw.w;
        o4[256 + t] = o;
        sw = s4[512 + 2 * t];             // cD1 lo
        o.x = e[8]  * sw.x; o.y = e[9]  * sw.y;
        o.z = e[10] * sw.z; o.w = e[11] * sw.w;
        o4[512 + 2 * t] = o;
        sw = s4[512 + 2 * t + 1];         // cD1 hi
        o.x = e[12] * sw.x; o.y = e[13] * sw.y;
        o.z = e[14] * sw.z; o.w = e[15] * sw.w;
        o4[512 + 2 * t + 1] = o;
    }
}

extern "C" void kernel_launch(void* const* d_in, const int* in_sizes, int n_in,
                              void* d_out, int out_size, void* d_ws, size_t ws_size,
                              hipStream_t stream) {
    // setup_inputs() order: x, diag_s, diag_g, diag_b, dec_lo, dec_hi, perm, scales
    const float* x      = (const float*)d_in[0];
    const float* diag_s = (const float*)d_in[1];
    const float* diag_g = (const float*)d_in[2];
    const float* diag_b = (const float*)d_in[3];
    const int* perm     = (const int*)d_in[6];
    float* out          = (float*)d_out;

    const int B = 4096 / R;
    wavelet_rows_kernel<<<B, NT, 0, stream>>>(x, diag_s, diag_g, diag_b, perm, out);
}